// Round 6
// baseline (418.790 us; speedup 1.0000x reference)
//
#include <hip/hip_runtime.h>
#include <hip/hip_bf16.h>

// ECE loss, train path:
//   conf[r]  = max(softmax(logits[r,:])) = 1 / sum(exp(l - max))
//   pred[r]  = argmax(logits[r,:])   (first index on ties, matches jnp.argmax)
//   bin      = clip(ceil(conf*10)-1, 0, 9)
//   ece      = sum_b |conf_sum/cnt - corr_sum/cnt| * cnt/N   over non-empty bins
//
// Memory-bound: 256 MB logits + 4 MB labels, floor ~40 us at 6.75 TB/s (fill-measured).
// R2 data: dur_us 369.7 but ~305 us of that is harness 1-GB ws-poison fills
// (151 us each, top-5 of rocprof). Controllable slice ~65 us. This round:
// fold final reduction into main kernel (last-block pattern), 2-row unroll.

#define N_BINS 10
#define C 64

// ws layout: [0..9] cnt, [10..19] conf_sum, [20..29] corr_sum (doubles), then counter.
#define WS_COUNTER_OFF 30  // in doubles

__global__ void ece_init_ws(double* ws) {
    int t = threadIdx.x;
    if (t < 3 * N_BINS) ws[t] = 0.0;
    if (t == 0) *(unsigned int*)(ws + WS_COUNTER_OFF) = 0u;
}

__device__ __forceinline__ void row_reduce(const float4 v, float& conf, int& idx) {
    // per-lane max + argmax (first index wins on ties)
    float m = v.x; int mi = 0;
    if (v.y > m) { m = v.y; mi = 1; }
    if (v.z > m) { m = v.z; mi = 2; }
    if (v.w > m) { m = v.w; mi = 3; }
    idx = ((threadIdx.x & 15) << 2) + mi;
    #pragma unroll
    for (int off = 1; off < 16; off <<= 1) {
        float om = __shfl_xor(m, off, 64);
        int   oi = __shfl_xor(idx, off, 64);
        if (om > m || (om == m && oi < idx)) { m = om; idx = oi; }
    }
    float se = __expf(v.x - m) + __expf(v.y - m) + __expf(v.z - m) + __expf(v.w - m);
    #pragma unroll
    for (int off = 1; off < 16; off <<= 1) se += __shfl_xor(se, off, 64);
    conf = 1.0f / se;
}

__global__ __launch_bounds__(256) void ece_main(const float* __restrict__ logits,
                                                const int* __restrict__ labels,
                                                double* __restrict__ gbins,
                                                float* __restrict__ out,
                                                int N) {
    __shared__ float s_cnt[N_BINS];
    __shared__ float s_conf[N_BINS];
    __shared__ float s_corr[N_BINS];
    __shared__ int s_last;
    const int tid = threadIdx.x;
    if (tid < N_BINS) {
        s_cnt[tid] = 0.0f;
        s_conf[tid] = 0.0f;
        s_corr[tid] = 0.0f;
    }
    __syncthreads();

    const int lane16 = tid & 15;
    const int group0 = (blockIdx.x * blockDim.x + tid) >> 4;
    const int ngroups = (gridDim.x * blockDim.x) >> 4;

    // 2-row unroll: two independent coalesced float4 loads + butterfly chains.
    for (int row = group0; row < N; row += 2 * ngroups) {
        const int row2 = row + ngroups;
        const float4 v1 = reinterpret_cast<const float4*>(logits + (size_t)row * C)[lane16];
        float4 v2;
        if (row2 < N) v2 = reinterpret_cast<const float4*>(logits + (size_t)row2 * C)[lane16];

        float conf1; int idx1;
        row_reduce(v1, conf1, idx1);
        float conf2 = 0.0f; int idx2 = 0;
        if (row2 < N) row_reduce(v2, conf2, idx2);

        if (lane16 == 0) {
            {
                int bin = min(max((int)ceilf(conf1 * (float)N_BINS) - 1, 0), N_BINS - 1);
                atomicAdd(&s_cnt[bin], 1.0f);
                atomicAdd(&s_conf[bin], conf1);
                if (idx1 == labels[row]) atomicAdd(&s_corr[bin], 1.0f);
            }
            if (row2 < N) {
                int bin = min(max((int)ceilf(conf2 * (float)N_BINS) - 1, 0), N_BINS - 1);
                atomicAdd(&s_cnt[bin], 1.0f);
                atomicAdd(&s_conf[bin], conf2);
                if (idx2 == labels[row2]) atomicAdd(&s_corr[bin], 1.0f);
            }
        }
    }
    __syncthreads();
    if (tid < N_BINS) {
        if (s_cnt[tid] != 0.0f) {
            atomicAdd(&gbins[tid], (double)s_cnt[tid]);
            atomicAdd(&gbins[N_BINS + tid], (double)s_conf[tid]);
            atomicAdd(&gbins[2 * N_BINS + tid], (double)s_corr[tid]);
        }
    }

    // Last-block-does-final: flush visible (threadfence) -> counter -> final.
    if (tid == 0) {
        __threadfence();
        unsigned int old = atomicAdd((unsigned int*)(gbins + WS_COUNTER_OFF), 1u);
        s_last = (old == gridDim.x - 1) ? 1 : 0;
    }
    __syncthreads();
    if (s_last && tid == 0) {
        __threadfence();
        double ece = 0.0;
        for (int b = 0; b < N_BINS; ++b) {
            // atomicAdd(p, 0.0) = coherent read at device scope (cross-XCD safe).
            double cnt = atomicAdd(&gbins[b], 0.0);
            if (cnt > 0.0) {
                double conf = atomicAdd(&gbins[N_BINS + b], 0.0) / cnt;
                double corr = atomicAdd(&gbins[2 * N_BINS + b], 0.0) / cnt;
                double d = conf - corr;
                if (d < 0.0) d = -d;
                ece += d * (cnt / (double)N);
            }
        }
        out[0] = (float)ece;
    }
}

extern "C" void kernel_launch(void* const* d_in, const int* in_sizes, int n_in,
                              void* d_out, int out_size, void* d_ws, size_t ws_size,
                              hipStream_t stream) {
    const float* logits = (const float*)d_in[0];
    const int* labels = (const int*)d_in[1];
    // d_in[2] is `train` (static 1) — the train branch is baked in at trace time.
    float* out = (float*)d_out;
    double* gbins = (double*)d_ws;

    const int N = in_sizes[1];  // 1,000,000 rows

    ece_init_ws<<<1, 64, 0, stream>>>(gbins);
    // 2048 blocks x 256 threads = 32768 row-groups (8 blocks/CU, 32 waves/CU max occupancy).
    ece_main<<<2048, 256, 0, stream>>>(logits, labels, gbins, out, N);
}